// Round 2
// baseline (2025.553 us; speedup 1.0000x reference)
//
#include <hip/hip_runtime.h>

#define TT 2048

typedef float v2f __attribute__((ext_vector_type(2)));
typedef _Float16 h2v __attribute__((ext_vector_type(2)));

__device__ __forceinline__ v2f mk2(float a, float b) { v2f r; r.x = a; r.y = b; return r; }
__device__ __forceinline__ float rcpf(float x) { return __builtin_amdgcn_rcpf(x); }
__device__ __forceinline__ float fsig(float x) { return rcpf(1.0f + __expf(-x)); }
__device__ __forceinline__ float ftanh(float x) {
    return fmaf(2.0f, rcpf(1.0f + __expf(-2.0f * x)), -1.0f);
}

template<int C>
__device__ __forceinline__ float dppmov(float s) {
    return __int_as_float(__builtin_amdgcn_update_dpp(
        __float_as_int(s), __float_as_int(s), C, 0xF, 0xF, false));
}
template<int Q>
__device__ __forceinline__ float qbcast(float x) {
    return __int_as_float(__builtin_amdgcn_update_dpp(
        __float_as_int(x), __float_as_int(x), Q * 0x55, 0xF, 0xF, false));
}

#if __has_builtin(__builtin_amdgcn_fdot2)
#define DOT2(a, b, c) __builtin_amdgcn_fdot2((a), (b), (c), false)
#else
#define DOT2(a, b, c) fmaf((float)(a).x, (float)(b).x, \
                      fmaf((float)(a).y, (float)(b).y, (c)))
#endif

__device__ __forceinline__ h2v pk2(float a, float b) {
#if __has_builtin(__builtin_amdgcn_cvt_pkrtz)
    return __builtin_bit_cast(h2v, __builtin_amdgcn_cvt_pkrtz(a, b));
#else
    h2v r; r.x = (_Float16)a; r.y = (_Float16)b; return r;
#endif
}
__device__ __forceinline__ h2v bch(int v) { return __builtin_bit_cast(h2v, v); }

// ===== Kernel 1: TWO ELEMENTS PER WAVE =====================================
// R24 post-mortem: R23's b32->b128 weight reads were NEUTRAL (877->888us,
// VALUBusy 38 both) -> NOT DS-throughput-bound. Revised model: latency-bound
// on the serial recurrence (1028cy/step vs ~300cy VALU issue; ring ds_read
// ~120cy + 16-deep dot chains + 5 sequential transcendentals), one lone wave
// per SIMD with nothing to fill stalls. Fix: interleave TWO independent
// elements in one wave (weights shared!). Issue ~600cy/step, chains overlap
// -> step ~650-720cy. 256 blocks, 1 wave/CU. ALL W1 weights in LDS (R23
// proved weights-from-LDS free; DS pipe now has 2x slack) to stay under the
// ~128-VGPR allocator cap (R19-R22). Opaque `off` blocks LICM from hoisting
// the loop-invariant weight loads into registers. Accumulation order is
// bit-identical to the passing kernel (kpg-major, component-minor).
__global__ __launch_bounds__(64)
__attribute__((amdgpu_waves_per_eu(1, 1)))
void lstm1_f16x2(const float* __restrict__ x,
                 const float* __restrict__ W1,
                 const float* __restrict__ b1,
                 const float* __restrict__ W2,
                 float* __restrict__ zout)
{
    __shared__ __align__(16) float xallA[TT];
    __shared__ __align__(16) float xallB[TT];
    __shared__ __align__(16) _Float16 hringA[16 * 72];   // 144B/slot
    __shared__ __align__(16) _Float16 hringB[16 * 72];
    __shared__ __align__(16) int wG4[4][8][64][4];       // [gate][kpg][u][kp&3]
    __shared__ __align__(16) _Float16 w2lds[4][72];

    const int lane = threadIdx.x & 63;
    const int u    = lane;
    const int e0   = blockIdx.x * 2;
    const int e1   = e0 + 1;

    for (int i = lane; i < TT; i += 64) {
        xallA[i] = x[(size_t)e0 * TT + i];
        xallB[i] = x[(size_t)e1 * TT + i];
    }
    for (int i = lane; i < 576; i += 64) {
        ((int*)hringA)[i] = 0;
        ((int*)hringB)[i] = 0;
    }
    // All 4 gate weight blocks into LDS as packed h2v pairs, 4 consecutive
    // kp per lane contiguous -> one ds_read_b128 covers 4 k-pairs.
    for (int g = 0; g < 4; ++g)
        for (int kp = 0; kp < 32; ++kp)
            wG4[g][kp >> 2][u][kp & 3] = __builtin_bit_cast(int,
                pk2(W1[(1 + 2*kp)*256 + g*64 + u],
                    W1[(2 + 2*kp)*256 + g*64 + u]));
    w2lds[0][lane] = (_Float16)W2[lane * 4 + 0];
    w2lds[1][lane] = (_Float16)W2[lane * 4 + 1];
    w2lds[2][lane] = (_Float16)W2[lane * 4 + 2];
    w2lds[3][lane] = (_Float16)W2[lane * 4 + 3];

    const float w0I = W1[u],        bI = b1[u];
    const float w0J = W1[64 + u],   bJ = b1[64 + u];
    const float w0F = W1[128 + u],  bF = b1[128 + u] + 1.0f;  // forget bias
    const float w0O = W1[192 + u],  bO = b1[192 + u];

    const int tl = lane >> 2, gq = lane & 3;   // layer-2 batch role

    float c1A = 0.0f, c1B = 0.0f;
    __syncthreads();   // single wave: covers init stores

    float* __restrict__ zbA = zout + (size_t)e0 * TT * 4;
    float* __restrict__ zbB = zout + (size_t)e1 * TT * 4;
    const int* __restrict__ wIb = &wG4[0][0][0][0] + (u << 2);  // + kpg*256 ints
    const int* __restrict__ wJb = &wG4[1][0][0][0] + (u << 2);
    const int* __restrict__ wFb = &wG4[2][0][0][0] + (u << 2);
    const int* __restrict__ wOb = &wG4[3][0][0][0] + (u << 2);

    // One kpg group: 4 weight b128 loads (shared by both elements),
    // 32 DOT2 (4 gates x 4 comps x 2 elements). Per-acc order identical
    // to the proven kernel: q.x, q.y, q.z, q.w within each kpg.
#define GDOT(S, g, qa, qb) { \
    const int4 wi_ = *(const int4*)(wIb + off + (g) * 256); \
    const int4 wj_ = *(const int4*)(wJb + off + (g) * 256); \
    const int4 wf_ = *(const int4*)(wFb + off + (g) * 256); \
    const int4 wo_ = *(const int4*)(wOb + off + (g) * 256); \
    accIA##S = DOT2(bch((qa).x), bch(wi_.x), accIA##S); \
    accJA##S = DOT2(bch((qa).x), bch(wj_.x), accJA##S); \
    accFA##S = DOT2(bch((qa).x), bch(wf_.x), accFA##S); \
    accOA##S = DOT2(bch((qa).x), bch(wo_.x), accOA##S); \
    accIB##S = DOT2(bch((qb).x), bch(wi_.x), accIB##S); \
    accJB##S = DOT2(bch((qb).x), bch(wj_.x), accJB##S); \
    accFB##S = DOT2(bch((qb).x), bch(wf_.x), accFB##S); \
    accOB##S = DOT2(bch((qb).x), bch(wo_.x), accOB##S); \
    accIA##S = DOT2(bch((qa).y), bch(wi_.y), accIA##S); \
    accJA##S = DOT2(bch((qa).y), bch(wj_.y), accJA##S); \
    accFA##S = DOT2(bch((qa).y), bch(wf_.y), accFA##S); \
    accOA##S = DOT2(bch((qa).y), bch(wo_.y), accOA##S); \
    accIB##S = DOT2(bch((qb).y), bch(wi_.y), accIB##S); \
    accJB##S = DOT2(bch((qb).y), bch(wj_.y), accJB##S); \
    accFB##S = DOT2(bch((qb).y), bch(wf_.y), accFB##S); \
    accOB##S = DOT2(bch((qb).y), bch(wo_.y), accOB##S); \
    accIA##S = DOT2(bch((qa).z), bch(wi_.z), accIA##S); \
    accJA##S = DOT2(bch((qa).z), bch(wj_.z), accJA##S); \
    accFA##S = DOT2(bch((qa).z), bch(wf_.z), accFA##S); \
    accOA##S = DOT2(bch((qa).z), bch(wo_.z), accOA##S); \
    accIB##S = DOT2(bch((qb).z), bch(wi_.z), accIB##S); \
    accJB##S = DOT2(bch((qb).z), bch(wj_.z), accJB##S); \
    accFB##S = DOT2(bch((qb).z), bch(wf_.z), accFB##S); \
    accOB##S = DOT2(bch((qb).z), bch(wo_.z), accOB##S); \
    accIA##S = DOT2(bch((qa).w), bch(wi_.w), accIA##S); \
    accJA##S = DOT2(bch((qa).w), bch(wj_.w), accJA##S); \
    accFA##S = DOT2(bch((qa).w), bch(wf_.w), accFA##S); \
    accOA##S = DOT2(bch((qa).w), bch(wo_.w), accOA##S); \
    accIB##S = DOT2(bch((qb).w), bch(wi_.w), accIB##S); \
    accJB##S = DOT2(bch((qb).w), bch(wj_.w), accJB##S); \
    accFB##S = DOT2(bch((qb).w), bch(wf_.w), accFB##S); \
    accOB##S = DOT2(bch((qb).w), bch(wo_.w), accOB##S); \
}

    for (int t = 0; t < TT; ++t) {
        // opaque zero: keeps per-step weight loads in the loop (no LICM hoist)
        int off = 0; asm volatile("" : "+v"(off));
        // h(t-1) ring reads for both elements (uniform-address broadcast b128)
        const int4* hpA = (const int4*)&hringA[((t - 1) & 15) * 72];
        const int4* hpB = (const int4*)&hringB[((t - 1) & 15) * 72];
        const int4 a0 = hpA[0], a1 = hpA[1], a2 = hpA[2], a3 = hpA[3];
        const int4 a4 = hpA[4], a5 = hpA[5], a6 = hpA[6], a7 = hpA[7];
        const int4 b0 = hpB[0], b1q = hpB[1], b2q = hpB[2], b3q = hpB[3];
        const int4 b4 = hpB[4], b5q = hpB[5], b6q = hpB[6], b7q = hpB[7];
        float accIA0 = bI, accJA0 = bJ, accFA0 = bF, accOA0 = bO;
        float accIA1 = 0.f, accJA1 = 0.f, accFA1 = 0.f, accOA1 = 0.f;
        float accIB0 = bI, accJB0 = bJ, accFB0 = bF, accOB0 = bO;
        float accIB1 = 0.f, accJB1 = 0.f, accFB1 = 0.f, accOB1 = 0.f;
        // kpg 0..3 -> chain 0, kpg 4..7 -> chain 1 (same split as proven kernel)
        GDOT(0, 0, a0, b0)  GDOT(1, 4, a4, b4)
        GDOT(0, 1, a1, b1q) GDOT(1, 5, a5, b5q)
        GDOT(0, 2, a2, b2q) GDOT(1, 6, a6, b6q)
        GDOT(0, 3, a3, b3q) GDOT(1, 7, a7, b7q)
        // x-part folded at the end
        const float xtA = xallA[t];
        const float xtB = xallB[t];
        const float zIA = fmaf(xtA, w0I, accIA0 + accIA1);
        const float zJA = fmaf(xtA, w0J, accJA0 + accJA1);
        const float zFA = fmaf(xtA, w0F, accFA0 + accFA1);
        const float zOA = fmaf(xtA, w0O, accOA0 + accOA1);
        const float zIB = fmaf(xtB, w0I, accIB0 + accIB1);
        const float zJB = fmaf(xtB, w0J, accJB0 + accJB1);
        const float zFB = fmaf(xtB, w0F, accFB0 + accFB1);
        const float zOB = fmaf(xtB, w0O, accOB0 + accOB1);
        // nonlinearities (all f32), two independent chains
        const float iA = fsig(zIA),  iB = fsig(zIB);
        const float jA = ftanh(zJA), jB = ftanh(zJB);
        const float fA = fsig(zFA),  fB = fsig(zFB);   // +1 folded into bF
        const float oA = fsig(zOA),  oB = fsig(zOB);
        c1A = fmaf(c1A, fA, iA * jA);
        c1B = fmaf(c1B, fB, iB * jB);
        const float h1A = ftanh(c1A) * oA;
        const float h1B = ftanh(c1B) * oB;
        hringA[(t & 15) * 72 + u] = (_Float16)h1A;   // same-wave visible (lgkm)
        hringB[(t & 15) * 72 + u] = (_Float16)h1B;

        // layer-2 partial batch every 16 steps (W2 from LDS), both elements
        if ((t & 15) == 15) {
            const int4* w2q = (const int4*)&w2lds[gq][0];
            const int4* hbA = (const int4*)&hringA[tl * 72];
            const int4* hbB = (const int4*)&hringB[tl * 72];
            float z2A = 0.0f, z2B = 0.0f;
#pragma unroll
            for (int q = 0; q < 8; ++q) {
                const int4 wv = w2q[q];
                const int4 va = hbA[q];
                const int4 vb = hbB[q];
                z2A = DOT2(bch(va.x), bch(wv.x), z2A);
                z2A = DOT2(bch(va.y), bch(wv.y), z2A);
                z2A = DOT2(bch(va.z), bch(wv.z), z2A);
                z2A = DOT2(bch(va.w), bch(wv.w), z2A);
                z2B = DOT2(bch(vb.x), bch(wv.x), z2B);
                z2B = DOT2(bch(vb.y), bch(wv.y), z2B);
                z2B = DOT2(bch(vb.z), bch(wv.z), z2B);
                z2B = DOT2(bch(vb.w), bch(wv.w), z2B);
            }
            zbA[(size_t)(t - 15 + tl) * 4 + gq] = z2A;   // lane-coalesced
            zbB[(size_t)(t - 15 + tl) * 4 + gq] = z2B;
        }
    }
#undef GDOT
}

// ===== Kernel 2: layer-2 recurrence (R13, proven, format unchanged) =====
__global__ __launch_bounds__(64)
void lstm2_chain(const float* __restrict__ zp,
                 const float* __restrict__ W2,
                 const float* __restrict__ b2,
                 float* __restrict__ out)
{
    const int lane = threadIdx.x & 63;
    const int e    = lane >> 2;
    const int g    = lane & 3;
    const int elem = (blockIdx.x << 4) + e;

    const float w2h = W2[256 + g];
    const float bb  = b2[g] + ((g == 2) ? 1.0f : 0.0f);
    const float nlm = (g == 1) ? -2.0f : -1.0f;
    const float k2  = (g == 1) ?  2.0f :  1.0f;
    const float k3  = (g == 1) ? -1.0f :  0.0f;

    const float* __restrict__ zrow = zp + (size_t)elem * TT * 4 + g;
    float* __restrict__ orow = out + (size_t)elem * TT;

    float c2 = 0.0f, h2 = 0.0f;

    float zc[16];
#pragma unroll
    for (int k = 0; k < 16; ++k) zc[k] = zrow[k << 2];

    for (int t0 = 0; t0 < TT; t0 += 16) {
        float zn[16];
        if (t0 + 16 < TT) {
#pragma unroll
            for (int k = 0; k < 16; ++k) zn[k] = zrow[((t0 + 16 + k) << 2)];
        }
        float st0 = 0.f, st1 = 0.f, st2 = 0.f, st3 = 0.f;
#pragma unroll
        for (int k = 0; k < 16; ++k) {
            const float arg = fmaf(w2h, h2, zc[k] + bb);
            const float ev  = __expf(arg * nlm);
            const float rv  = rcpf(1.0f + ev);
            const float v   = fmaf(k2, rv, k3);
            const float vi = qbcast<0>(v), vj = qbcast<1>(v);
            const float vf = qbcast<2>(v), vo = qbcast<3>(v);
            c2 = fmaf(c2, vf, vi * vj);
            h2 = ftanh(c2) * vo;
            const bool mine = (g == (k & 3));
            if ((k >> 2) == 0) st0 = mine ? h2 : st0;
            else if ((k >> 2) == 1) st1 = mine ? h2 : st1;
            else if ((k >> 2) == 2) st2 = mine ? h2 : st2;
            else st3 = mine ? h2 : st3;
        }
        orow[t0 + g]      = st0;
        orow[t0 + 4 + g]  = st1;
        orow[t0 + 8 + g]  = st2;
        orow[t0 + 12 + g] = st3;
#pragma unroll
        for (int k = 0; k < 16; ++k) zc[k] = zn[k];
    }
}

// ===== Fallback: monolithic (R11 core, proven) =====
__global__ __launch_bounds__(512)
__attribute__((amdgpu_waves_per_eu(4, 4)))
void lstm2_mono(const float* __restrict__ x,
                const float* __restrict__ W1,
                const float* __restrict__ b1,
                const float* __restrict__ W2,
                const float* __restrict__ b2,
                float* __restrict__ out)
{
    __shared__ __align__(16) float xall[TT + 4];
    __shared__ __align__(16) float h1x[2][80];
    __shared__ __align__(16) float zpq[4][4];
    __shared__ __align__(16) float h2buf[2][64];

    const int tid  = threadIdx.x;
    const int wave = tid >> 6;
    const int lane = tid & 63;
    const int b    = blockIdx.x;

    for (int i = tid; i < TT; i += 512) xall[i] = x[b * TT + i];
    if (tid < 4) xall[TT + tid] = 0.0f;

    const int u    = lane >> 3;
    const int h    = (lane >> 2) & 1;
    const int g    = lane & 3;
    const int unit = (wave << 3) + u;
    const int col  = (g << 6) + unit;

#define DECLW(k) const v2f wq##k = mk2(W1[(1 + 32*h + 2*(k)) * 256 + col], \
                                       W1[(2 + 32*h + 2*(k)) * 256 + col]);
    DECLW(0)  DECLW(1)  DECLW(2)  DECLW(3)
    DECLW(4)  DECLW(5)  DECLW(6)  DECLW(7)
    DECLW(8)  DECLW(9)  DECLW(10) DECLW(11)
    DECLW(12) DECLW(13) DECLW(14) DECLW(15)
#undef DECLW

    const float w0x   = (h == 0) ? W1[col] : 0.0f;
    const float biasF = (h == 0) ? (b1[col] + ((g == 2) ? 1.0f : 0.0f)) : 0.0f;
    const float nlm   = (g == 1) ? -2.0f : -1.0f;
    const bool  isj   = (g == 1);

    const float w2g  = W2[lane * 4 + (wave & 3)];
    const float w2h0 = W2[256], w2h1 = W2[257], w2h2 = W2[258], w2h3 = W2[259];
    const float b20 = b2[0], b21 = b2[1], b22 = b2[2], b23 = b2[3];

    float c1 = 0.0f;
    float c2 = 0.0f, h2v2 = 0.0f;

    const int hbase = h * 48;
    const int ridx  = lane + ((lane >> 5) << 4);
    const int widx  = (unit < 32) ? unit : unit + 16;

    if (tid < 160) ((float*)h1x)[tid] = 0.0f;
    __syncthreads();

    float* __restrict__ outb = out + b * TT;

#define WSUM(s) ({ float _s = (s);                                            \
    _s += dppmov<0x111>(_s); _s += dppmov<0x112>(_s); _s += dppmov<0x114>(_s);\
    _s += dppmov<0x118>(_s); _s += dppmov<0x142>(_s); _s += dppmov<0x143>(_s);\
    _s; })

#define STEP(P, t, xv)                                                        \
    {                                                                         \
        if ((t) < TT) {                                                       \
            const float4* hp = (const float4*)&h1x[P][hbase];                 \
            const float4 q0 = hp[0], q1 = hp[1], q2 = hp[2], q3 = hp[3];      \
            const float4 q4 = hp[4], q5 = hp[5], q6 = hp[6], q7 = hp[7];      \
            v2f a0 = mk2(fmaf((xv), w0x, biasF), 0.0f);                       \
            v2f a1 = mk2(0.f, 0.f), a2 = mk2(0.f, 0.f), a3 = mk2(0.f, 0.f);  \
            a0 = __builtin_elementwise_fma(mk2(q0.x, q0.y), wq0,  a0);        \
            a1 = __builtin_elementwise_fma(mk2(q0.z, q0.w), wq1,  a1);        \
            a2 = __builtin_elementwise_fma(mk2(q1.x, q1.y), wq2,  a2);        \
            a3 = __builtin_elementwise_fma(mk2(q1.z, q1.w), wq3,  a3);        \
            a0 = __builtin_elementwise_fma(mk2(q2.x, q2.y), wq4,  a0);        \
            a1 = __builtin_elementwise_fma(mk2(q2.z, q2.w), wq5,  a1);        \
            a2 = __builtin_elementwise_fma(mk2(q3.x, q3.y), wq6,  a2);        \
            a3 = __builtin_elementwise_fma(mk2(q3.z, q3.w), wq7,  a3);        \
            a0 = __builtin_elementwise_fma(mk2(q4.x, q4.y), wq8,  a0);        \
            a1 = __builtin_elementwise_fma(mk2(q4.z, q4.w), wq9,  a1);        \
            a2 = __builtin_elementwise_fma(mk2(q5.x, q5.y), wq10, a2);        \
            a3 = __builtin_elementwise_fma(mk2(q5.z, q5.w), wq11, a3);        \
            a0 = __builtin_elementwise_fma(mk2(q6.x, q6.y), wq12, a0);        \
            a1 = __builtin_elementwise_fma(mk2(q6.z, q6.w), wq13, a1);        \
            a2 = __builtin_elementwise_fma(mk2(q7.x, q7.y), wq14, a2);        \
            a3 = __builtin_elementwise_fma(mk2(q7.z, q7.w), wq15, a3);        \
            const v2f sv = (a0 + a1) + (a2 + a3);                             \
            const float zh = sv.x + sv.y;                                     \
            const float tshr = dppmov<0x114>(zh);                             \
            const float tshl = dppmov<0x104>(zh);                             \
            const float zfull = zh + (h ? tshr : tshl);                       \
            const float e = __expf(zfull * nlm);                              \
            const float r = rcpf(1.0f + e);                                   \
            const float v = isj ? fmaf(2.0f, r, -1.0f) : r;                   \
            const float gi = qbcast<0>(v), gj = qbcast<1>(v);                 \
            const float gf = qbcast<2>(v), go = qbcast<3>(v);                 \
            c1 = fmaf(c1, gf, gi * gj);                                       \
            const float h1v = ftanh(c1) * go;                                 \
            if ((lane & 7) == 0) h1x[(P) ^ 1][widx] = h1v;                    \
        }                                                                     \
        if (wave < 4 && (t) >= 1 && (t) <= TT) {                              \
            const float s = WSUM(h1x[P][ridx] * w2g);                         \
            if (lane == 63) zpq[((t) - 1) & 3][wave] = s;                     \
        }                                                                     \
        if (wave == 7 && lane == 0 && (t) >= 2 && (t) <= TT + 1) {            \
            const int st = (t) - 2;                                           \
            const float4 z4 = *(const float4*)zpq[st & 3];                    \
            const float zi = z4.x + fmaf(h2v2, w2h0, b20);                    \
            const float zj = z4.y + fmaf(h2v2, w2h1, b21);                    \
            const float zf = z4.z + fmaf(h2v2, w2h2, b22);                    \
            const float zo = z4.w + fmaf(h2v2, w2h3, b23);                    \
            c2 = c2 * fsig(zf + 1.0f) + fsig(zi) * ftanh(zj);                 \
            h2v2 = ftanh(c2) * fsig(zo);                                      \
            h2buf[(st >> 6) & 1][st & 63] = h2v2;                             \
        }                                                                     \
        __syncthreads();                                                      \
        if (wave == 4 && (t) >= 66 && ((t) & 63) == 2) {                      \
            const int blk = ((t) - 66) >> 6;                                  \
            outb[(blk << 6) + lane] = h2buf[blk & 1][lane];                   \
        }                                                                     \
    }

    for (int it = 0; it <= TT + 2; it += 2) {
        const float2 x2 = *(const float2*)&xall[it];
        STEP(0, it,     x2.x)
        STEP(1, it + 1, x2.y)
    }
#undef STEP
#undef WSUM
}

extern "C" void kernel_launch(void* const* d_in, const int* in_sizes, int n_in,
                              void* d_out, int out_size, void* d_ws, size_t ws_size,
                              hipStream_t stream)
{
    const float* x  = (const float*)d_in[0];
    const float* W1 = (const float*)d_in[1];
    const float* b1 = (const float*)d_in[2];
    const float* W2 = (const float*)d_in[3];
    const float* b2 = (const float*)d_in[4];
    float* out = (float*)d_out;

    const size_t need = (size_t)512 * TT * 4 * sizeof(float);   // 16.8 MB
    if (ws_size >= need) {
        float* zp = (float*)d_ws;
        lstm1_f16x2<<<256, 64, 0, stream>>>(x, W1, b1, W2, zp);
        lstm2_chain<<<512 / 16, 64, 0, stream>>>(zp, W2, b2, out);
    } else {
        lstm2_mono<<<512, 512, 0, stream>>>(x, W1, b1, W2, b2, out);
    }
}

// Round 3
// 1488.447 us; speedup vs baseline: 1.3609x; 1.3609x over previous
//
#include <hip/hip_runtime.h>

#define TT 2048

typedef float v2f __attribute__((ext_vector_type(2)));
typedef _Float16 h2v __attribute__((ext_vector_type(2)));

__device__ __forceinline__ v2f mk2(float a, float b) { v2f r; r.x = a; r.y = b; return r; }
__device__ __forceinline__ float rcpf(float x) { return __builtin_amdgcn_rcpf(x); }
__device__ __forceinline__ float fsig(float x) { return rcpf(1.0f + __expf(-x)); }
__device__ __forceinline__ float ftanh(float x) {
    return fmaf(2.0f, rcpf(1.0f + __expf(-2.0f * x)), -1.0f);
}

template<int C>
__device__ __forceinline__ float dppmov(float s) {
    return __int_as_float(__builtin_amdgcn_update_dpp(
        __float_as_int(s), __float_as_int(s), C, 0xF, 0xF, false));
}
template<int Q>
__device__ __forceinline__ float qbcast(float x) {
    return __int_as_float(__builtin_amdgcn_update_dpp(
        __float_as_int(x), __float_as_int(x), Q * 0x55, 0xF, 0xF, false));
}

#if __has_builtin(__builtin_amdgcn_fdot2)
#define DOT2(a, b, c) __builtin_amdgcn_fdot2((a), (b), (c), false)
#else
#define DOT2(a, b, c) fmaf((float)(a).x, (float)(b).x, \
                      fmaf((float)(a).y, (float)(b).y, (c)))
#endif

__device__ __forceinline__ h2v pk2(float a, float b) {
#if __has_builtin(__builtin_amdgcn_cvt_pkrtz)
    return __builtin_bit_cast(h2v, __builtin_amdgcn_cvt_pkrtz(a, b));
#else
    h2v r; r.x = (_Float16)a; r.y = (_Float16)b; return r;
#endif
}
__device__ __forceinline__ h2v bch(int v) { return __builtin_bit_cast(h2v, v); }

// ===== Kernel 1: K-SPLIT — 2 waves per element, one per SIMD ===============
// R25 post-mortem chain: R23 (DS-width) neutral; R24 (2 elem/wave) = exactly
// 2x time, per-active-SIMD VALU util ~70-76% in BOTH configs -> the kernel is
// PER-WAVE ISSUE-BOUND (in-order wave64, >=2cy/op). Only lever: more SIMDs
// per element. This kernel splits k: wave w owns k=32w..32w+31, ALL 4 gates'
// half-k weights in REGISTERS (64 h2v — budget R1 proved grants). Per step:
// 64 dots/wave (was 128), float4 partial-sum exchange via double-buffered LDS
// + ONE barrier, then both waves redundantly compute gates/c1/h1 (state
// coherent, no 2nd barrier) and write their own ring half (each wave only
// READS its own half -> ring needs no sync). Batch layer-2 phase every 16
// steps reads both halves -> bracketed by 2 barriers there (amortized).
// 512 blocks x 128 thr = 4 waves/CU on 4 SIMDs.
__global__ __launch_bounds__(128)
__attribute__((amdgpu_waves_per_eu(1)))
void lstm1_ks2(const float* __restrict__ x,
               const float* __restrict__ W1,
               const float* __restrict__ b1,
               const float* __restrict__ W2,
               float* __restrict__ zout)
{
    __shared__ __align__(16) float xall[TT];
    __shared__ __align__(16) _Float16 hring[16 * 72];   // 144B/slot
    __shared__ __align__(16) float4 pex[2][2][64];      // [t&1][wave][u]
    __shared__ __align__(16) _Float16 w2lds[4][72];

    const int tid  = threadIdx.x;
    const int w    = tid >> 6;        // wave: 0 -> k 0..31, 1 -> k 32..63
    const int u    = tid & 63;
    const int e    = blockIdx.x;
    const int kbase = w << 4;         // k-pair base: 0 or 16

    for (int i = tid; i < TT; i += 128) xall[i] = x[(size_t)e * TT + i];
    for (int i = tid; i < 576; i += 128) ((int*)hring)[i] = 0;
    if (tid < 64) {
        w2lds[0][u] = (_Float16)W2[u * 4 + 0];
        w2lds[1][u] = (_Float16)W2[u * 4 + 1];
        w2lds[2][u] = (_Float16)W2[u * 4 + 2];
        w2lds[3][u] = (_Float16)W2[u * 4 + 3];
    }

    // All 4 gates' half-k weights in registers: 16 h2v per gate.
#define DWQ(G, GO, q) \
    const h2v w##G##q##x = pk2(W1[(1+2*(kbase+4*(q)+0))*256 + (GO)*64 + u], \
                               W1[(2+2*(kbase+4*(q)+0))*256 + (GO)*64 + u]); \
    const h2v w##G##q##y = pk2(W1[(1+2*(kbase+4*(q)+1))*256 + (GO)*64 + u], \
                               W1[(2+2*(kbase+4*(q)+1))*256 + (GO)*64 + u]); \
    const h2v w##G##q##z = pk2(W1[(1+2*(kbase+4*(q)+2))*256 + (GO)*64 + u], \
                               W1[(2+2*(kbase+4*(q)+2))*256 + (GO)*64 + u]); \
    const h2v w##G##q##w = pk2(W1[(1+2*(kbase+4*(q)+3))*256 + (GO)*64 + u], \
                               W1[(2+2*(kbase+4*(q)+3))*256 + (GO)*64 + u]);
    DWQ(I, 0, 0) DWQ(I, 0, 1) DWQ(I, 0, 2) DWQ(I, 0, 3)
    DWQ(J, 1, 0) DWQ(J, 1, 1) DWQ(J, 1, 2) DWQ(J, 1, 3)
    DWQ(F, 2, 0) DWQ(F, 2, 1) DWQ(F, 2, 2) DWQ(F, 2, 3)
    DWQ(O, 3, 0) DWQ(O, 3, 1) DWQ(O, 3, 2) DWQ(O, 3, 3)
#undef DWQ

    const float w0I = W1[u];
    const float w0J = W1[64 + u];
    const float w0F = W1[128 + u];
    const float w0O = W1[192 + u];
    // biases folded into wave0's accumulator init only
    const float aI = (w == 0) ? b1[u]              : 0.0f;
    const float aJ = (w == 0) ? b1[64 + u]         : 0.0f;
    const float aF = (w == 0) ? (b1[128 + u] + 1.0f) : 0.0f;  // forget bias
    const float aO = (w == 0) ? b1[192 + u]        : 0.0f;

    const int tl = u >> 2, gq = u & 3;   // layer-2 batch role (wave0 only)

    float c1 = 0.0f;
    __syncthreads();   // init visible to both waves

    float* __restrict__ zb = zout + (size_t)e * TT * 4;

    // one ring quad (4 h2v) against one 4-pack of weight h2v, into acc
#define DG(acc, WQ, qv) \
    acc = DOT2(bch((qv).x), WQ##x, acc); \
    acc = DOT2(bch((qv).y), WQ##y, acc); \
    acc = DOT2(bch((qv).z), WQ##z, acc); \
    acc = DOT2(bch((qv).w), WQ##w, acc);

    for (int t = 0; t < TT; ++t) {
        // own-half ring quads (written by this wave last step — no sync needed)
        const int4* hp = (const int4*)&hring[((t - 1) & 15) * 72];
        const int4 q0 = hp[(w << 2) + 0], q1 = hp[(w << 2) + 1];
        const int4 q2 = hp[(w << 2) + 2], q3 = hp[(w << 2) + 3];
        float accI0 = aI, accJ0 = aJ, accF0 = aF, accO0 = aO;
        float accI1 = 0.f, accJ1 = 0.f, accF1 = 0.f, accO1 = 0.f;
        // 64 dots: 2 chains per gate (8-deep) for latency headroom
        DG(accI0, wI0, q0) DG(accJ0, wJ0, q0) DG(accF0, wF0, q0) DG(accO0, wO0, q0)
        DG(accI0, wI1, q1) DG(accJ0, wJ1, q1) DG(accF0, wF1, q1) DG(accO0, wO1, q1)
        DG(accI1, wI2, q2) DG(accJ1, wJ2, q2) DG(accF1, wF2, q2) DG(accO1, wO2, q2)
        DG(accI1, wI3, q3) DG(accJ1, wJ3, q3) DG(accF1, wF3, q3) DG(accO1, wO3, q3)
        const float mI = accI0 + accI1;
        const float mJ = accJ0 + accJ1;
        const float mF = accF0 + accF1;
        const float mO = accO0 + accO1;
        // exchange partials (double-buffered by t&1)
        pex[t & 1][w][u] = make_float4(mI, mJ, mF, mO);
        __syncthreads();
        const float4 po = pex[t & 1][w ^ 1][u];
        const float xt = xall[t];
        const float zI = fmaf(xt, w0I, mI + po.x);
        const float zJ = fmaf(xt, w0J, mJ + po.y);
        const float zF = fmaf(xt, w0F, mF + po.z);
        const float zO = fmaf(xt, w0O, mO + po.w);
        // nonlinearities — both waves redundantly (state stays coherent)
        const float i_ = fsig(zI);
        const float j_ = ftanh(zJ);
        const float f_ = fsig(zF);            // +1 folded into aF
        const float o_ = fsig(zO);
        c1 = fmaf(c1, f_, i_ * j_);
        const float h1 = ftanh(c1) * o_;
        // each wave writes ONLY its own k-half of the ring
        if ((u >> 5) == w) hring[(t & 15) * 72 + u] = (_Float16)h1;

        // layer-2 partial batch every 16 steps (wave0; needs both halves)
        if ((t & 15) == 15) {
            __syncthreads();               // full ring (both halves) visible
            if (w == 0) {
                const int4* hb  = (const int4*)&hring[tl * 72];
                const int4* w2q = (const int4*)&w2lds[gq][0];
                float z2 = 0.0f;
#pragma unroll
                for (int q = 0; q < 8; ++q) {
                    const int4 wv = w2q[q];
                    const int4 va = hb[q];
                    z2 = DOT2(bch(va.x), bch(wv.x), z2);
                    z2 = DOT2(bch(va.y), bch(wv.y), z2);
                    z2 = DOT2(bch(va.z), bch(wv.z), z2);
                    z2 = DOT2(bch(va.w), bch(wv.w), z2);
                }
                zb[(size_t)(t - 15 + tl) * 4 + gq] = z2;   // lane-coalesced
            }
            __syncthreads();               // protect batch reads from t+1 writes
        }
    }
#undef DG
}

// ===== Kernel 2: layer-2 recurrence (R13, proven, format unchanged) =====
__global__ __launch_bounds__(64)
void lstm2_chain(const float* __restrict__ zp,
                 const float* __restrict__ W2,
                 const float* __restrict__ b2,
                 float* __restrict__ out)
{
    const int lane = threadIdx.x & 63;
    const int e    = lane >> 2;
    const int g    = lane & 3;
    const int elem = (blockIdx.x << 4) + e;

    const float w2h = W2[256 + g];
    const float bb  = b2[g] + ((g == 2) ? 1.0f : 0.0f);
    const float nlm = (g == 1) ? -2.0f : -1.0f;
    const float k2  = (g == 1) ?  2.0f :  1.0f;
    const float k3  = (g == 1) ? -1.0f :  0.0f;

    const float* __restrict__ zrow = zp + (size_t)elem * TT * 4 + g;
    float* __restrict__ orow = out + (size_t)elem * TT;

    float c2 = 0.0f, h2 = 0.0f;

    float zc[16];
#pragma unroll
    for (int k = 0; k < 16; ++k) zc[k] = zrow[k << 2];

    for (int t0 = 0; t0 < TT; t0 += 16) {
        float zn[16];
        if (t0 + 16 < TT) {
#pragma unroll
            for (int k = 0; k < 16; ++k) zn[k] = zrow[((t0 + 16 + k) << 2)];
        }
        float st0 = 0.f, st1 = 0.f, st2 = 0.f, st3 = 0.f;
#pragma unroll
        for (int k = 0; k < 16; ++k) {
            const float arg = fmaf(w2h, h2, zc[k] + bb);
            const float ev  = __expf(arg * nlm);
            const float rv  = rcpf(1.0f + ev);
            const float v   = fmaf(k2, rv, k3);
            const float vi = qbcast<0>(v), vj = qbcast<1>(v);
            const float vf = qbcast<2>(v), vo = qbcast<3>(v);
            c2 = fmaf(c2, vf, vi * vj);
            h2 = ftanh(c2) * vo;
            const bool mine = (g == (k & 3));
            if ((k >> 2) == 0) st0 = mine ? h2 : st0;
            else if ((k >> 2) == 1) st1 = mine ? h2 : st1;
            else if ((k >> 2) == 2) st2 = mine ? h2 : st2;
            else st3 = mine ? h2 : st3;
        }
        orow[t0 + g]      = st0;
        orow[t0 + 4 + g]  = st1;
        orow[t0 + 8 + g]  = st2;
        orow[t0 + 12 + g] = st3;
#pragma unroll
        for (int k = 0; k < 16; ++k) zc[k] = zn[k];
    }
}

// ===== Fallback: monolithic (R11 core, proven) =====
__global__ __launch_bounds__(512)
__attribute__((amdgpu_waves_per_eu(4, 4)))
void lstm2_mono(const float* __restrict__ x,
                const float* __restrict__ W1,
                const float* __restrict__ b1,
                const float* __restrict__ W2,
                const float* __restrict__ b2,
                float* __restrict__ out)
{
    __shared__ __align__(16) float xall[TT + 4];
    __shared__ __align__(16) float h1x[2][80];
    __shared__ __align__(16) float zpq[4][4];
    __shared__ __align__(16) float h2buf[2][64];

    const int tid  = threadIdx.x;
    const int wave = tid >> 6;
    const int lane = tid & 63;
    const int b    = blockIdx.x;

    for (int i = tid; i < TT; i += 512) xall[i] = x[b * TT + i];
    if (tid < 4) xall[TT + tid] = 0.0f;

    const int u    = lane >> 3;
    const int h    = (lane >> 2) & 1;
    const int g    = lane & 3;
    const int unit = (wave << 3) + u;
    const int col  = (g << 6) + unit;

#define DECLW(k) const v2f wq##k = mk2(W1[(1 + 32*h + 2*(k)) * 256 + col], \
                                       W1[(2 + 32*h + 2*(k)) * 256 + col]);
    DECLW(0)  DECLW(1)  DECLW(2)  DECLW(3)
    DECLW(4)  DECLW(5)  DECLW(6)  DECLW(7)
    DECLW(8)  DECLW(9)  DECLW(10) DECLW(11)
    DECLW(12) DECLW(13) DECLW(14) DECLW(15)
#undef DECLW

    const float w0x   = (h == 0) ? W1[col] : 0.0f;
    const float biasF = (h == 0) ? (b1[col] + ((g == 2) ? 1.0f : 0.0f)) : 0.0f;
    const float nlm   = (g == 1) ? -2.0f : -1.0f;
    const bool  isj   = (g == 1);

    const float w2g  = W2[lane * 4 + (wave & 3)];
    const float w2h0 = W2[256], w2h1 = W2[257], w2h2 = W2[258], w2h3 = W2[259];
    const float b20 = b2[0], b21 = b2[1], b22 = b2[2], b23 = b2[3];

    float c1 = 0.0f;
    float c2 = 0.0f, h2v2 = 0.0f;

    const int hbase = h * 48;
    const int ridx  = lane + ((lane >> 5) << 4);
    const int widx  = (unit < 32) ? unit : unit + 16;

    if (tid < 160) ((float*)h1x)[tid] = 0.0f;
    __syncthreads();

    float* __restrict__ outb = out + b * TT;

#define WSUM(s) ({ float _s = (s);                                            \
    _s += dppmov<0x111>(_s); _s += dppmov<0x112>(_s); _s += dppmov<0x114>(_s);\
    _s += dppmov<0x118>(_s); _s += dppmov<0x142>(_s); _s += dppmov<0x143>(_s);\
    _s; })

#define STEP(P, t, xv)                                                        \
    {                                                                         \
        if ((t) < TT) {                                                       \
            const float4* hp = (const float4*)&h1x[P][hbase];                 \
            const float4 q0 = hp[0], q1 = hp[1], q2 = hp[2], q3 = hp[3];      \
            const float4 q4 = hp[4], q5 = hp[5], q6 = hp[6], q7 = hp[7];      \
            v2f a0 = mk2(fmaf((xv), w0x, biasF), 0.0f);                       \
            v2f a1 = mk2(0.f, 0.f), a2 = mk2(0.f, 0.f), a3 = mk2(0.f, 0.f);  \
            a0 = __builtin_elementwise_fma(mk2(q0.x, q0.y), wq0,  a0);        \
            a1 = __builtin_elementwise_fma(mk2(q0.z, q0.w), wq1,  a1);        \
            a2 = __builtin_elementwise_fma(mk2(q1.x, q1.y), wq2,  a2);        \
            a3 = __builtin_elementwise_fma(mk2(q1.z, q1.w), wq3,  a3);        \
            a0 = __builtin_elementwise_fma(mk2(q2.x, q2.y), wq4,  a0);        \
            a1 = __builtin_elementwise_fma(mk2(q2.z, q2.w), wq5,  a1);        \
            a2 = __builtin_elementwise_fma(mk2(q3.x, q3.y), wq6,  a2);        \
            a3 = __builtin_elementwise_fma(mk2(q3.z, q3.w), wq7,  a3);        \
            a0 = __builtin_elementwise_fma(mk2(q4.x, q4.y), wq8,  a0);        \
            a1 = __builtin_elementwise_fma(mk2(q4.z, q4.w), wq9,  a1);        \
            a2 = __builtin_elementwise_fma(mk2(q5.x, q5.y), wq10, a2);        \
            a3 = __builtin_elementwise_fma(mk2(q5.z, q5.w), wq11, a3);        \
            a0 = __builtin_elementwise_fma(mk2(q6.x, q6.y), wq12, a0);        \
            a1 = __builtin_elementwise_fma(mk2(q6.z, q6.w), wq13, a1);        \
            a2 = __builtin_elementwise_fma(mk2(q7.x, q7.y), wq14, a2);        \
            a3 = __builtin_elementwise_fma(mk2(q7.z, q7.w), wq15, a3);        \
            const v2f sv = (a0 + a1) + (a2 + a3);                             \
            const float zh = sv.x + sv.y;                                     \
            const float tshr = dppmov<0x114>(zh);                             \
            const float tshl = dppmov<0x104>(zh);                             \
            const float zfull = zh + (h ? tshr : tshl);                       \
            const float e = __expf(zfull * nlm);                              \
            const float r = rcpf(1.0f + e);                                   \
            const float v = isj ? fmaf(2.0f, r, -1.0f) : r;                   \
            const float gi = qbcast<0>(v), gj = qbcast<1>(v);                 \
            const float gf = qbcast<2>(v), go = qbcast<3>(v);                 \
            c1 = fmaf(c1, gf, gi * gj);                                       \
            const float h1v = ftanh(c1) * go;                                 \
            if ((lane & 7) == 0) h1x[(P) ^ 1][widx] = h1v;                    \
        }                                                                     \
        if (wave < 4 && (t) >= 1 && (t) <= TT) {                              \
            const float s = WSUM(h1x[P][ridx] * w2g);                         \
            if (lane == 63) zpq[((t) - 1) & 3][wave] = s;                     \
        }                                                                     \
        if (wave == 7 && lane == 0 && (t) >= 2 && (t) <= TT + 1) {            \
            const int st = (t) - 2;                                           \
            const float4 z4 = *(const float4*)zpq[st & 3];                    \
            const float zi = z4.x + fmaf(h2v2, w2h0, b20);                    \
            const float zj = z4.y + fmaf(h2v2, w2h1, b21);                    \
            const float zf = z4.z + fmaf(h2v2, w2h2, b22);                    \
            const float zo = z4.w + fmaf(h2v2, w2h3, b23);                    \
            c2 = c2 * fsig(zf + 1.0f) + fsig(zi) * ftanh(zj);                 \
            h2v2 = ftanh(c2) * fsig(zo);                                      \
            h2buf[(st >> 6) & 1][st & 63] = h2v2;                             \
        }                                                                     \
        __syncthreads();                                                      \
        if (wave == 4 && (t) >= 66 && ((t) & 63) == 2) {                      \
            const int blk = ((t) - 66) >> 6;                                  \
            outb[(blk << 6) + lane] = h2buf[blk & 1][lane];                   \
        }                                                                     \
    }

    for (int it = 0; it <= TT + 2; it += 2) {
        const float2 x2 = *(const float2*)&xall[it];
        STEP(0, it,     x2.x)
        STEP(1, it + 1, x2.y)
    }
#undef STEP
#undef WSUM
}

extern "C" void kernel_launch(void* const* d_in, const int* in_sizes, int n_in,
                              void* d_out, int out_size, void* d_ws, size_t ws_size,
                              hipStream_t stream)
{
    const float* x  = (const float*)d_in[0];
    const float* W1 = (const float*)d_in[1];
    const float* b1 = (const float*)d_in[2];
    const float* W2 = (const float*)d_in[3];
    const float* b2 = (const float*)d_in[4];
    float* out = (float*)d_out;

    const size_t need = (size_t)512 * TT * 4 * sizeof(float);   // 16.8 MB
    if (ws_size >= need) {
        float* zp = (float*)d_ws;
        lstm1_ks2<<<512, 128, 0, stream>>>(x, W1, b1, W2, zp);
        lstm2_chain<<<512 / 16, 64, 0, stream>>>(zp, W2, b2, out);
    } else {
        lstm2_mono<<<512, 512, 0, stream>>>(x, W1, b1, W2, b2, out);
    }
}

// Round 4
// 1410.995 us; speedup vs baseline: 1.4355x; 1.0549x over previous
//
#include <hip/hip_runtime.h>

#define TT 2048

typedef float v2f __attribute__((ext_vector_type(2)));
typedef _Float16 h2v __attribute__((ext_vector_type(2)));
typedef _Float16 f16x8 __attribute__((ext_vector_type(8)));
typedef float f32x4 __attribute__((ext_vector_type(4)));

__device__ __forceinline__ v2f mk2(float a, float b) { v2f r; r.x = a; r.y = b; return r; }
__device__ __forceinline__ float rcpf(float x) { return __builtin_amdgcn_rcpf(x); }
__device__ __forceinline__ float fsig(float x) { return rcpf(1.0f + __expf(-x)); }
__device__ __forceinline__ float ftanh(float x) {
    return fmaf(2.0f, rcpf(1.0f + __expf(-2.0f * x)), -1.0f);
}

template<int C>
__device__ __forceinline__ float dppmov(float s) {
    return __int_as_float(__builtin_amdgcn_update_dpp(
        __float_as_int(s), __float_as_int(s), C, 0xF, 0xF, false));
}
template<int Q>
__device__ __forceinline__ float qbcast(float x) {
    return __int_as_float(__builtin_amdgcn_update_dpp(
        __float_as_int(x), __float_as_int(x), Q * 0x55, 0xF, 0xF, false));
}

#if __has_builtin(__builtin_amdgcn_fdot2)
#define DOT2(a, b, c) __builtin_amdgcn_fdot2((a), (b), (c), false)
#else
#define DOT2(a, b, c) fmaf((float)(a).x, (float)(b).x, \
                      fmaf((float)(a).y, (float)(b).y, (c)))
#endif

__device__ __forceinline__ h2v bch(int v) { return __builtin_bit_cast(h2v, v); }

// ===== Kernel 1: MFMA matvec — matrix pipe does the dots ===================
// R26. Triangulated model (R23 DS-width neutral; R24 2elem/wave = exactly 2x;
// R25 k-split+barrier = regression): per-wave VALU-ISSUE bound, v_dot2 ~4cy,
// 128 dots/step = ~512cy of the ~780 busy cy. Fix: move the matvec
// h(64) @ W1h(64x256) to the MATRIX pipe: 32x v_mfma_f32_16x16x32_f16
// (16 N-tiles x 2 K-tiles). h is broadcast into ALL 16 A-rows (A-frag read =
// 2x ds_read_b128 from the ring, addr depends only on lane>>4), so every D
// row equals z and the verified C/D map (col = lane&15) gives every lane its
// column's z in .x of each tile acc. Lane u selects its 4 gate z's from
// tiles 4g+(u>>4) with 3 cndmask per gate — no LDS scatter, no barriers.
// 32 loop-invariant B-frags (128 h2v) + 16 accs ride the unified VGPR/AGPR
// file (1 wave/SIMD -> 512 regs available). VALU now does only select+
// nonlin (~50 ops); MFMA pipe ~160cy/step runs in parallel.
__global__ __launch_bounds__(64)
__attribute__((amdgpu_waves_per_eu(1)))
void lstm1_mfma(const float* __restrict__ x,
                const float* __restrict__ W1,
                const float* __restrict__ b1,
                const float* __restrict__ W2,
                float* __restrict__ zout)
{
    __shared__ __align__(16) float xall[TT];
    __shared__ __align__(16) _Float16 hring[16 * 72];  // 144B/slot, 16B-aligned lane-chunks
    __shared__ __align__(16) _Float16 w2lds[4][72];

    const int lane = threadIdx.x & 63;
    const int e    = blockIdx.x;
    const int u    = lane;
    const int lg   = lane >> 4;      // k-chunk / row-group
    const int j16  = lane & 15;      // column within tile

    for (int i = lane; i < TT; i += 64) xall[i] = x[(size_t)e * TT + i];
    for (int i = lane; i < 576; i += 64) ((int*)hring)[i] = 0;
    w2lds[0][lane] = (_Float16)W2[lane * 4 + 0];
    w2lds[1][lane] = (_Float16)W2[lane * 4 + 1];
    w2lds[2][lane] = (_Float16)W2[lane * 4 + 2];
    w2lds[3][lane] = (_Float16)W2[lane * 4 + 3];

    // B-fragments: tile n covers z columns 16n..16n+15; K-tile kt covers
    // k = 32kt..32kt+31. Lane l holds B[k = kt*32 + (l>>4)*8 + j][16n + (l&15)],
    // j = 0..7 (standard square-MFMA operand layout; slot-pairing with the
    // identically-built A makes the dot correct for any HW k-permutation).
#define MKB(kt, n) ({ f16x8 f_; \
    _Pragma("unroll") \
    for (int j = 0; j < 8; ++j) \
        f_[j] = (_Float16)W1[(size_t)(1 + (kt)*32 + lg*8 + j) * 256 + 16*(n) + j16]; \
    f_; })
    const f16x8 wB0_0  = MKB(0,0),  wB0_1  = MKB(0,1),  wB0_2  = MKB(0,2),  wB0_3  = MKB(0,3);
    const f16x8 wB0_4  = MKB(0,4),  wB0_5  = MKB(0,5),  wB0_6  = MKB(0,6),  wB0_7  = MKB(0,7);
    const f16x8 wB0_8  = MKB(0,8),  wB0_9  = MKB(0,9),  wB0_10 = MKB(0,10), wB0_11 = MKB(0,11);
    const f16x8 wB0_12 = MKB(0,12), wB0_13 = MKB(0,13), wB0_14 = MKB(0,14), wB0_15 = MKB(0,15);
    const f16x8 wB1_0  = MKB(1,0),  wB1_1  = MKB(1,1),  wB1_2  = MKB(1,2),  wB1_3  = MKB(1,3);
    const f16x8 wB1_4  = MKB(1,4),  wB1_5  = MKB(1,5),  wB1_6  = MKB(1,6),  wB1_7  = MKB(1,7);
    const f16x8 wB1_8  = MKB(1,8),  wB1_9  = MKB(1,9),  wB1_10 = MKB(1,10), wB1_11 = MKB(1,11);
    const f16x8 wB1_12 = MKB(1,12), wB1_13 = MKB(1,13), wB1_14 = MKB(1,14), wB1_15 = MKB(1,15);
#undef MKB

    const float w0I = W1[u],        bI = b1[u];
    const float w0J = W1[64 + u],   bJ = b1[64 + u];
    const float w0F = W1[128 + u],  bF = b1[128 + u] + 1.0f;  // forget bias
    const float w0O = W1[192 + u],  bO = b1[192 + u];

    const int tl = lane >> 2, gq = lane & 3;   // layer-2 batch role

    float c1 = 0.0f;
    __syncthreads();   // single wave: covers init stores

    float* __restrict__ zb = zout + (size_t)e * TT * 4;
    const f32x4 zf = {0.0f, 0.0f, 0.0f, 0.0f};

#define MM(a, b, c) __builtin_amdgcn_mfma_f32_16x16x32_f16((a), (b), (c), 0, 0, 0)
#define TACC(n) const f32x4 ac##n = MM(A1, wB1_##n, MM(A0, wB0_##n, zf));

    for (int t = 0; t < TT; ++t) {
        // A-fragments: h(t-1) broadcast into all 16 rows. Lane l reads
        // halves [kt*32 + (l>>4)*8 .. +8) — address depends only on l>>4.
        const int slot = ((t - 1) & 15) * 72;
        const f16x8 A0 = *(const f16x8*)&hring[slot + lg * 8];
        const f16x8 A1 = *(const f16x8*)&hring[slot + 32 + lg * 8];
        // 32 MFMA: tile n accumulates K-tile0 then K-tile1
        TACC(0)  TACC(1)  TACC(2)  TACC(3)
        TACC(4)  TACC(5)  TACC(6)  TACC(7)
        TACC(8)  TACC(9)  TACC(10) TACC(11)
        TACC(12) TACC(13) TACC(14) TACC(15)
        // gate select: z_g[u] lives in tile 4g + (u>>4), col u&15, reg .x
        const float zIs = (lg == 0) ? ac0.x  : (lg == 1) ? ac1.x  : (lg == 2) ? ac2.x  : ac3.x;
        const float zJs = (lg == 0) ? ac4.x  : (lg == 1) ? ac5.x  : (lg == 2) ? ac6.x  : ac7.x;
        const float zFs = (lg == 0) ? ac8.x  : (lg == 1) ? ac9.x  : (lg == 2) ? ac10.x : ac11.x;
        const float zOs = (lg == 0) ? ac12.x : (lg == 1) ? ac13.x : (lg == 2) ? ac14.x : ac15.x;
        // x-part + bias folded at the end
        const float xt = xall[t];
        const float zI = fmaf(xt, w0I, zIs + bI);
        const float zJ = fmaf(xt, w0J, zJs + bJ);
        const float zF = fmaf(xt, w0F, zFs + bF);
        const float zO = fmaf(xt, w0O, zOs + bO);
        // nonlinearities (all f32)
        const float i_ = fsig(zI);
        const float j_ = ftanh(zJ);
        const float f_ = fsig(zF);            // +1 folded into bF
        const float o_ = fsig(zO);
        c1 = fmaf(c1, f_, i_ * j_);
        const float h1 = ftanh(c1) * o_;
        hring[(t & 15) * 72 + u] = (_Float16)h1;   // same-wave visible (lgkm)

        // layer-2 partial batch every 16 steps (W2 from LDS)
        if ((t & 15) == 15) {
            const int4* hb  = (const int4*)&hring[tl * 72];
            const int4* w2q = (const int4*)&w2lds[gq][0];
            float z2 = 0.0f;
#pragma unroll
            for (int q = 0; q < 8; ++q) {
                const int4 wv = w2q[q];
                const int4 va = hb[q];
                z2 = DOT2(bch(va.x), bch(wv.x), z2);
                z2 = DOT2(bch(va.y), bch(wv.y), z2);
                z2 = DOT2(bch(va.z), bch(wv.z), z2);
                z2 = DOT2(bch(va.w), bch(wv.w), z2);
            }
            zb[(size_t)(t - 15 + tl) * 4 + gq] = z2;   // lane-coalesced
        }
    }
#undef TACC
#undef MM
}

// ===== Kernel 2: layer-2 recurrence (R13, proven, format unchanged) =====
__global__ __launch_bounds__(64)
void lstm2_chain(const float* __restrict__ zp,
                 const float* __restrict__ W2,
                 const float* __restrict__ b2,
                 float* __restrict__ out)
{
    const int lane = threadIdx.x & 63;
    const int e    = lane >> 2;
    const int g    = lane & 3;
    const int elem = (blockIdx.x << 4) + e;

    const float w2h = W2[256 + g];
    const float bb  = b2[g] + ((g == 2) ? 1.0f : 0.0f);
    const float nlm = (g == 1) ? -2.0f : -1.0f;
    const float k2  = (g == 1) ?  2.0f :  1.0f;
    const float k3  = (g == 1) ? -1.0f :  0.0f;

    const float* __restrict__ zrow = zp + (size_t)elem * TT * 4 + g;
    float* __restrict__ orow = out + (size_t)elem * TT;

    float c2 = 0.0f, h2 = 0.0f;

    float zc[16];
#pragma unroll
    for (int k = 0; k < 16; ++k) zc[k] = zrow[k << 2];

    for (int t0 = 0; t0 < TT; t0 += 16) {
        float zn[16];
        if (t0 + 16 < TT) {
#pragma unroll
            for (int k = 0; k < 16; ++k) zn[k] = zrow[((t0 + 16 + k) << 2)];
        }
        float st0 = 0.f, st1 = 0.f, st2 = 0.f, st3 = 0.f;
#pragma unroll
        for (int k = 0; k < 16; ++k) {
            const float arg = fmaf(w2h, h2, zc[k] + bb);
            const float ev  = __expf(arg * nlm);
            const float rv  = rcpf(1.0f + ev);
            const float v   = fmaf(k2, rv, k3);
            const float vi = qbcast<0>(v), vj = qbcast<1>(v);
            const float vf = qbcast<2>(v), vo = qbcast<3>(v);
            c2 = fmaf(c2, vf, vi * vj);
            h2 = ftanh(c2) * vo;
            const bool mine = (g == (k & 3));
            if ((k >> 2) == 0) st0 = mine ? h2 : st0;
            else if ((k >> 2) == 1) st1 = mine ? h2 : st1;
            else if ((k >> 2) == 2) st2 = mine ? h2 : st2;
            else st3 = mine ? h2 : st3;
        }
        orow[t0 + g]      = st0;
        orow[t0 + 4 + g]  = st1;
        orow[t0 + 8 + g]  = st2;
        orow[t0 + 12 + g] = st3;
#pragma unroll
        for (int k = 0; k < 16; ++k) zc[k] = zn[k];
    }
}

// ===== Fallback: monolithic (R11 core, proven) =====
__global__ __launch_bounds__(512)
__attribute__((amdgpu_waves_per_eu(4, 4)))
void lstm2_mono(const float* __restrict__ x,
                const float* __restrict__ W1,
                const float* __restrict__ b1,
                const float* __restrict__ W2,
                const float* __restrict__ b2,
                float* __restrict__ out)
{
    __shared__ __align__(16) float xall[TT + 4];
    __shared__ __align__(16) float h1x[2][80];
    __shared__ __align__(16) float zpq[4][4];
    __shared__ __align__(16) float h2buf[2][64];

    const int tid  = threadIdx.x;
    const int wave = tid >> 6;
    const int lane = tid & 63;
    const int b    = blockIdx.x;

    for (int i = tid; i < TT; i += 512) xall[i] = x[b * TT + i];
    if (tid < 4) xall[TT + tid] = 0.0f;

    const int u    = lane >> 3;
    const int h    = (lane >> 2) & 1;
    const int g    = lane & 3;
    const int unit = (wave << 3) + u;
    const int col  = (g << 6) + unit;

#define DECLW(k) const v2f wq##k = mk2(W1[(1 + 32*h + 2*(k)) * 256 + col], \
                                       W1[(2 + 32*h + 2*(k)) * 256 + col]);
    DECLW(0)  DECLW(1)  DECLW(2)  DECLW(3)
    DECLW(4)  DECLW(5)  DECLW(6)  DECLW(7)
    DECLW(8)  DECLW(9)  DECLW(10) DECLW(11)
    DECLW(12) DECLW(13) DECLW(14) DECLW(15)
#undef DECLW

    const float w0x   = (h == 0) ? W1[col] : 0.0f;
    const float biasF = (h == 0) ? (b1[col] + ((g == 2) ? 1.0f : 0.0f)) : 0.0f;
    const float nlm   = (g == 1) ? -2.0f : -1.0f;
    const bool  isj   = (g == 1);

    const float w2g  = W2[lane * 4 + (wave & 3)];
    const float w2h0 = W2[256], w2h1 = W2[257], w2h2 = W2[258], w2h3 = W2[259];
    const float b20 = b2[0], b21 = b2[1], b22 = b2[2], b23 = b2[3];

    float c1 = 0.0f;
    float c2 = 0.0f, h2v2 = 0.0f;

    const int hbase = h * 48;
    const int ridx  = lane + ((lane >> 5) << 4);
    const int widx  = (unit < 32) ? unit : unit + 16;

    if (tid < 160) ((float*)h1x)[tid] = 0.0f;
    __syncthreads();

    float* __restrict__ outb = out + b * TT;

#define WSUM(s) ({ float _s = (s);                                            \
    _s += dppmov<0x111>(_s); _s += dppmov<0x112>(_s); _s += dppmov<0x114>(_s);\
    _s += dppmov<0x118>(_s); _s += dppmov<0x142>(_s); _s += dppmov<0x143>(_s);\
    _s; })

#define STEP(P, t, xv)                                                        \
    {                                                                         \
        if ((t) < TT) {                                                       \
            const float4* hp = (const float4*)&h1x[P][hbase];                 \
            const float4 q0 = hp[0], q1 = hp[1], q2 = hp[2], q3 = hp[3];      \
            const float4 q4 = hp[4], q5 = hp[5], q6 = hp[6], q7 = hp[7];      \
            v2f a0 = mk2(fmaf((xv), w0x, biasF), 0.0f);                       \
            v2f a1 = mk2(0.f, 0.f), a2 = mk2(0.f, 0.f), a3 = mk2(0.f, 0.f);  \
            a0 = __builtin_elementwise_fma(mk2(q0.x, q0.y), wq0,  a0);        \
            a1 = __builtin_elementwise_fma(mk2(q0.z, q0.w), wq1,  a1);        \
            a2 = __builtin_elementwise_fma(mk2(q1.x, q1.y), wq2,  a2);        \
            a3 = __builtin_elementwise_fma(mk2(q1.z, q1.w), wq3,  a3);        \
            a0 = __builtin_elementwise_fma(mk2(q2.x, q2.y), wq4,  a0);        \
            a1 = __builtin_elementwise_fma(mk2(q2.z, q2.w), wq5,  a1);        \
            a2 = __builtin_elementwise_fma(mk2(q3.x, q3.y), wq6,  a2);        \
            a3 = __builtin_elementwise_fma(mk2(q3.z, q3.w), wq7,  a3);        \
            a0 = __builtin_elementwise_fma(mk2(q4.x, q4.y), wq8,  a0);        \
            a1 = __builtin_elementwise_fma(mk2(q4.z, q4.w), wq9,  a1);        \
            a2 = __builtin_elementwise_fma(mk2(q5.x, q5.y), wq10, a2);        \
            a3 = __builtin_elementwise_fma(mk2(q5.z, q5.w), wq11, a3);        \
            a0 = __builtin_elementwise_fma(mk2(q6.x, q6.y), wq12, a0);        \
            a1 = __builtin_elementwise_fma(mk2(q6.z, q6.w), wq13, a1);        \
            a2 = __builtin_elementwise_fma(mk2(q7.x, q7.y), wq14, a2);        \
            a3 = __builtin_elementwise_fma(mk2(q7.z, q7.w), wq15, a3);        \
            const v2f sv = (a0 + a1) + (a2 + a3);                             \
            const float zh = sv.x + sv.y;                                     \
            const float tshr = dppmov<0x114>(zh);                             \
            const float tshl = dppmov<0x104>(zh);                             \
            const float zfull = zh + (h ? tshr : tshl);                       \
            const float e = __expf(zfull * nlm);                              \
            const float r = rcpf(1.0f + e);                                   \
            const float v = isj ? fmaf(2.0f, r, -1.0f) : r;                   \
            const float gi = qbcast<0>(v), gj = qbcast<1>(v);                 \
            const float gf = qbcast<2>(v), go = qbcast<3>(v);                 \
            c1 = fmaf(c1, gf, gi * gj);                                       \
            const float h1v = ftanh(c1) * go;                                 \
            if ((lane & 7) == 0) h1x[(P) ^ 1][widx] = h1v;                    \
        }                                                                     \
        if (wave < 4 && (t) >= 1 && (t) <= TT) {                              \
            const float s = WSUM(h1x[P][ridx] * w2g);                         \
            if (lane == 63) zpq[((t) - 1) & 3][wave] = s;                     \
        }                                                                     \
        if (wave == 7 && lane == 0 && (t) >= 2 && (t) <= TT + 1) {            \
            const int st = (t) - 2;                                           \
            const float4 z4 = *(const float4*)zpq[st & 3];                    \
            const float zi = z4.x + fmaf(h2v2, w2h0, b20);                    \
            const float zj = z4.y + fmaf(h2v2, w2h1, b21);                    \
            const float zf = z4.z + fmaf(h2v2, w2h2, b22);                    \
            const float zo = z4.w + fmaf(h2v2, w2h3, b23);                    \
            c2 = c2 * fsig(zf + 1.0f) + fsig(zi) * ftanh(zj);                 \
            h2v2 = ftanh(c2) * fsig(zo);                                      \
            h2buf[(st >> 6) & 1][st & 63] = h2v2;                             \
        }                                                                     \
        __syncthreads();                                                      \
        if (wave == 4 && (t) >= 66 && ((t) & 63) == 2) {                      \
            const int blk = ((t) - 66) >> 6;                                  \
            outb[(blk << 6) + lane] = h2buf[blk & 1][lane];                   \
        }                                                                     \
    }

    for (int it = 0; it <= TT + 2; it += 2) {
        const float2 x2 = *(const float2*)&xall[it];
        STEP(0, it,     x2.x)
        STEP(1, it + 1, x2.y)
    }
#undef STEP
#undef WSUM
}

extern "C" void kernel_launch(void* const* d_in, const int* in_sizes, int n_in,
                              void* d_out, int out_size, void* d_ws, size_t ws_size,
                              hipStream_t stream)
{
    const float* x  = (const float*)d_in[0];
    const float* W1 = (const float*)d_in[1];
    const float* b1 = (const float*)d_in[2];
    const float* W2 = (const float*)d_in[3];
    const float* b2 = (const float*)d_in[4];
    float* out = (float*)d_out;

    const size_t need = (size_t)512 * TT * 4 * sizeof(float);   // 16.8 MB
    if (ws_size >= need) {
        float* zp = (float*)d_ws;
        lstm1_mfma<<<512, 64, 0, stream>>>(x, W1, b1, W2, zp);
        lstm2_chain<<<512 / 16, 64, 0, stream>>>(zp, W2, b2, out);
    } else {
        lstm2_mono<<<512, 512, 0, stream>>>(x, W1, b1, W2, b2, out);
    }
}